// Round 10
// baseline (7716.748 us; speedup 1.0000x reference)
//
#include <hip/hip_runtime.h>

// ScaledODENetFE: forward-Euler scan, T=44100, B=32, F=1, S=16, H=64.
// One wave per batch; lane k owns hidden unit k. Chain+issue bound;
// ~1-1.5 ns per VALU op removed (R2->R3, R6->R8 calibration).
// R9 over R8 (all linear-fold class, outputs contract to the bf16 floor):
//  - r-form butterfly: h = 1-2r is affine in r=rcp(1+t) -> butterfly runs on
//    r with weights -2*W2; pconst_s = sum_k W2[k,s] folds into the R-seed.
//    p0 = pconst0 + Pb0 per step (y0 keeps full-magnitude resolution).
//  - K-fold (K=2log2e): carry V=K*v via scaled w1x/b1/w1yd/c -> no mul in
//    the exp2 chain. t=exp2(z); d=t+1; r=rcp(d) feeds products directly.
//  - rotation combine: 15 INDEPENDENT dpp row_ror:i of Pb + per-lane
//    pre-permuted weights wrot[i]=W1YD[((lane&15)-i)&15] (row_ror receives
//    from (l-i)&15, same direction as R2's validated row_shr reduction).
//    Replaces 16 v_readlane (SGPR hazards) with VALU-only gathers.
// permlane16/32_swap BANNED (R4/R5). LDS P-broadcast BANNED on-chain (R7).

#define SRATE 44100.0f
#define T_TOTAL 44100
#define BATCH 32
#define HID 64
#define ST 16
#define KSCALE 2.8853900817779268f   // 2*log2(e)

typedef float v2f __attribute__((ext_vector_type(2)));

template <int CTRL>
__device__ __forceinline__ float dppmov(float x) {
    return __builtin_bit_cast(float,
        __builtin_amdgcn_update_dpp(0, __builtin_bit_cast(int, x),
                                    CTRL, 0xF, 0xF, false));
}

__device__ __forceinline__ float bcast(float v, int lane) {
    return __builtin_bit_cast(float,
        __builtin_amdgcn_readlane(__builtin_bit_cast(int, v), lane));
}

__device__ __forceinline__ int parity(int v) { return __builtin_popcount(v) & 1; }

// row_ror:i gather of x (receive from row-lane (l-i)&15), i=1..15.
template <int I>
__device__ __forceinline__ float rot(float x) { return dppmov<0x120 + I>(x); }

__global__ __launch_bounds__(64, 1)
void ScaledODENetFE_kernel(const float* __restrict__ x,
                           const float* __restrict__ W1,
                           const float* __restrict__ b1,
                           const float* __restrict__ W2,
                           const float* __restrict__ b2v,
                           float* __restrict__ out) {
    const int b = blockIdx.x;      // batch element
    const int lane = threadIdx.x;  // hidden unit k
    const int TM1 = T_TOTAL - 1;   // 44099 scan steps

    // ---- one-time precompute (lane k) ----
    const float w1xK = W1[lane] * KSCALE;       // K-scaled x weight
    float w1yd[ST];                             // K * W1[1+s][lane] / sr
    #pragma unroll
    for (int s = 0; s < ST; ++s)
        w1yd[s] = (W1[(1 + s) * HID + lane] / SRATE) * KSCALE;

    // pconst_s = sum_k W2[k,s]; C2 = K*c + sum_s pconst_s * w1yd[s].
    float C2 = 0.f;
    #pragma unroll
    for (int s = 0; s < ST; ++s) C2 = fmaf(b2v[s], w1yd[s], C2);
    float pconst0 = 0.f;
    for (int s = 0; s < ST; ++s) {
        float pc = 0.f;
        for (int k = 0; k < HID; ++k) pc += W2[k * ST + s];
        C2 = fmaf(pc, w1yd[s], C2);
        if (s == 0) pconst0 = pc;
    }

    // Rotation-combine weights: at rotation i, lane sees Pb_{(q-i)&15}.
    const int q = lane & 15;
    float wrot[ST];
    #pragma unroll
    for (int i = 0; i < ST; ++i) wrot[i] = w1yd[(q - i) & 15];

    // Dual-basis lane phis for the permuted W2 layout (XOR gens 1,2,7,8),
    // weights pre-scaled by -2 (r-form: p = pconst - 2 * W2^T r).
    const int p1 = parity(lane & 5), p2 = parity(lane & 6);
    const int p3 = (lane >> 2) & 1, p4 = (lane >> 3) & 1;
    float wA[8], wB[8];
    #pragma unroll
    for (int j = 0; j < 8; ++j) {
        const int i = 2 * j;
        const int c1 = (i & 1) ^ p1;
        const int c2 = ((i >> 1) & 1) ^ p2;
        const int c3 = ((i >> 2) & 1) ^ p3;
        const int c4 = ((i >> 3) & 1) ^ p4;
        const int s = (c1 ? 1 : 0) ^ (c2 ? 2 : 0) ^ (c3 ? 7 : 0) ^ (c4 ? 8 : 0);
        wA[j] = -2.f * W2[lane * ST + s];
        wB[j] = -2.f * W2[(lane ^ 1) * ST + s];
    }
    v2f wA2[4], wB2[4];
    #pragma unroll
    for (int m = 0; m < 4; ++m) {
        wA2[m] = (v2f){wA[2 * m], wA[2 * m + 1]};
        wB2[m] = (v2f){wB[2 * m], wB[2 * m + 1]};
    }

    const int bp32 = ((lane ^ 32) & 63) << 2;   // ds_bpermute byte addrs
    const int bp48 = ((lane ^ 48) & 63) << 2;
    const float b20 = b2v[0];

    float V  = b1[lane] * KSCALE;               // K-scaled carry
    float y0 = 0.f;

    if (lane == 0) out[b] = 0.f;                // row t=0 is zeros

    // Lane l holds x[(t0+l)*B + b]; prefetch one chunk ahead.
    float xv = x[min(lane, TM1 - 1) * BATCH + b];
    float z = fmaf(bcast(xv, 0), w1xK, V);      // seed step 0 (K-scaled)

    for (int t0 = 0; t0 < TM1; t0 += 64) {
        float xvn = x[min(t0 + 64 + lane, TM1 - 1) * BATCH + b];
        const int nsteps = min(64, TM1 - t0);
        float outy = 0.f;

        for (int kk = 0; kk < nsteps; ++kk) {
            // tanh chain in r-form: t=exp2(z); r=rcp(t+1); h=1-2r implicit.
            float t = __builtin_amdgcn_exp2f(z);
            float r = __builtin_amdgcn_rcpf(t + 1.f);

            // Off-chain prep for next step's z.
            const int nk = kk + 1;
            float xsrc = (nk == 64) ? xvn : xv;
            float xtn  = bcast(xsrc, nk & 63);
            float zbase = fmaf(xtn, w1xK, V);

            // Stage 1 (xor1, fused, packed) on r with -2-scaled weights.
            float rx = dppmov<0xB1>(r);         // quad_perm [1,0,3,2]
            v2f r2v = (v2f){r, r};
            v2f rx2 = (v2f){rx, rx};
            v2f u1p[4];
            #pragma unroll
            for (int m = 0; m < 4; ++m)
                u1p[m] = __builtin_elementwise_fma(rx2, wB2[m], r2v * wA2[m]);

            // Stage 2 (xor2 = quad_perm [2,3,0,1]).
            float u2[4];
            #pragma unroll
            for (int m = 0; m < 4; ++m)
                u2[m] = u1p[m].x + dppmov<0x4E>(u1p[m].y);

            // Stage 3 (xor7 = row_half_mirror).
            float u3a = u2[0] + dppmov<0x141>(u2[1]);
            float u3b = u2[2] + dppmov<0x141>(u2[3]);

            // Stage 4 (xor8 = row_ror:8).
            float Pb = u3a + dppmov<0x128>(u3b);

            // Cross-row combine: 3 INDEPENDENT DS ops, one latency (R6).
            int   Pi  = __builtin_bit_cast(int, Pb);
            float a16 = __builtin_bit_cast(float,
                        __builtin_amdgcn_ds_swizzle(Pi, 0x401F));       // ^16
            float a32 = __builtin_bit_cast(float,
                        __builtin_amdgcn_ds_bpermute(bp32, Pi));        // ^32
            float a48 = __builtin_bit_cast(float,
                        __builtin_amdgcn_ds_bpermute(bp48, Pi));        // ^48
            Pb = (Pb + a16) + (a32 + a48);
            // Lane holds Pb_{lane&15}; p_s = pconst_s + Pb_s.

            // y0 path: p0 = pconst0 + Pb0 (full magnitude), b20 at store.
            y0 += pconst0 + bcast(Pb, 0);
            outy = (kk == lane) ? y0 : outy;

            // R = C2 + sum_s Pb_s*w1yd[s] via 15 independent row_ror
            // gathers + per-lane pre-permuted weights; 4 chains depth 4.
            float g1  = rot<1>(Pb),  g2  = rot<2>(Pb),  g3  = rot<3>(Pb);
            float g4  = rot<4>(Pb),  g5  = rot<5>(Pb),  g6  = rot<6>(Pb);
            float g7  = rot<7>(Pb),  g8  = rot<8>(Pb),  g9  = rot<9>(Pb);
            float g10 = rot<10>(Pb), g11 = rot<11>(Pb), g12 = rot<12>(Pb);
            float g13 = rot<13>(Pb), g14 = rot<14>(Pb), g15 = rot<15>(Pb);
            float r0 = fmaf(Pb,  wrot[0],  C2);
            float r1 = g1  * wrot[1];
            float r2c = g2 * wrot[2];
            float r3c = g3 * wrot[3];
            r0 = fmaf(g4,  wrot[4],  r0);
            r1 = fmaf(g5,  wrot[5],  r1);
            r2c = fmaf(g6,  wrot[6],  r2c);
            r3c = fmaf(g7,  wrot[7],  r3c);
            r0 = fmaf(g8,  wrot[8],  r0);
            r1 = fmaf(g9,  wrot[9],  r1);
            r2c = fmaf(g10, wrot[10], r2c);
            r3c = fmaf(g11, wrot[11], r3c);
            r0 = fmaf(g12, wrot[12], r0);
            r1 = fmaf(g13, wrot[13], r1);
            r2c = fmaf(g14, wrot[14], r2c);
            r3c = fmaf(g15, wrot[15], r3c);
            float R = (r0 + r1) + (r2c + r3c);

            z = zbase + R;       // critical-path tail: single add
            V = V + R;           // off-chain, feeds next step's zbase
        }

        // Store: add back n*b2[0] (runtime-zero), one IEEE div, coalesced.
        if (lane < nsteps) {
            const int n = t0 + 1 + lane;
            out[n * BATCH + b] = fmaf((float)n, b20, outy) / SRATE;
        }
        xv = xvn;
    }
}

extern "C" void kernel_launch(void* const* d_in, const int* in_sizes, int n_in,
                              void* d_out, int out_size, void* d_ws, size_t ws_size,
                              hipStream_t stream) {
    const float* x  = (const float*)d_in[0];
    const float* W1 = (const float*)d_in[1];
    const float* b1 = (const float*)d_in[2];
    const float* W2 = (const float*)d_in[3];
    const float* b2 = (const float*)d_in[4];
    float* out = (float*)d_out;

    ScaledODENetFE_kernel<<<BATCH, 64, 0, stream>>>(x, W1, b1, W2, b2, out);
}

// Round 12
// 7117.353 us; speedup vs baseline: 1.0842x; 1.0842x over previous
//
#include <hip/hip_runtime.h>

// ScaledODENetFE: forward-Euler scan, T=44100, B=32, F=1, S=16, H=64.
// One wave per batch; lane k owns hidden unit k. Chain-latency bound.
// R11 = R8 skeleton + R9-validated algebra ONLY (R10's tail cuts reverted):
//  - r-form: butterfly runs on r=rcp(1+exp2(z)) with -2-scaled W2;
//    pconst_s = sum_k W2[k,s] folded into C2; p0 = pconst0 + Pb0.
//  - K-fold (K=2log2e): carry V=K*v; exp2 input needs no multiply.
//  - R materialized at its own scale (C2-seeded combine), then
//    z = zbase + R (on-chain add), V = V + R (off-chain). R10's
//    V' = V + ((z'-zC)+C2) reconstruction BANNED: cancellation of large
//    intermediates injects ulp(z)-scale noise into the carry each step
//    (absmax 2.86e-6 > 2.42e-6 threshold). Reassociation inside R is free;
//    carry reconstruction by subtracting large values is not.
// permlane16/32_swap BANNED (R4/R5). LDS P-broadcast BANNED (R7).
// Rotation combine RETIRED (R9 neutral-negative).

#define SRATE 44100.0f
#define T_TOTAL 44100
#define BATCH 32
#define HID 64
#define ST 16
#define KSCALE 2.8853900817779268f   // 2*log2(e)

typedef float v2f __attribute__((ext_vector_type(2)));

template <int CTRL>
__device__ __forceinline__ float dppmov(float x) {
    return __builtin_bit_cast(float,
        __builtin_amdgcn_update_dpp(0, __builtin_bit_cast(int, x),
                                    CTRL, 0xF, 0xF, false));
}

__device__ __forceinline__ float bcast(float v, int lane) {
    return __builtin_bit_cast(float,
        __builtin_amdgcn_readlane(__builtin_bit_cast(int, v), lane));
}

__device__ __forceinline__ int parity(int v) { return __builtin_popcount(v) & 1; }

__global__ __launch_bounds__(64, 1)
void ScaledODENetFE_kernel(const float* __restrict__ x,
                           const float* __restrict__ W1,
                           const float* __restrict__ b1,
                           const float* __restrict__ W2,
                           const float* __restrict__ b2v,
                           float* __restrict__ out) {
    const int b = blockIdx.x;      // batch element
    const int lane = threadIdx.x;  // hidden unit k
    const int TM1 = T_TOTAL - 1;   // 44099 scan steps

    // ---- one-time precompute (lane k) ----
    const float w1xK = W1[lane] * KSCALE;       // K-scaled x weight
    float w1yd[ST];                             // K * W1[1+s][lane] / sr
    #pragma unroll
    for (int s = 0; s < ST; ++s)
        w1yd[s] = (W1[(1 + s) * HID + lane] / SRATE) * KSCALE;

    // C2 = sum_s (b2[s] + pconst_s) * w1yd[s];  pconst_s = sum_k W2[k,s].
    float C2 = 0.f;
    #pragma unroll
    for (int s = 0; s < ST; ++s) C2 = fmaf(b2v[s], w1yd[s], C2);
    float pconst0 = 0.f;
    for (int s = 0; s < ST; ++s) {
        float pc = 0.f;
        for (int k = 0; k < HID; ++k) pc += W2[k * ST + s];
        C2 = fmaf(pc, w1yd[s], C2);
        if (s == 0) pconst0 = pc;
    }

    // Dual-basis lane phis for the permuted W2 layout (XOR gens 1,2,7,8),
    // weights pre-scaled by -2 (r-form: p = pconst - 2 * W2^T r).
    const int p1 = parity(lane & 5), p2 = parity(lane & 6);
    const int p3 = (lane >> 2) & 1, p4 = (lane >> 3) & 1;
    float wA[8], wB[8];
    #pragma unroll
    for (int j = 0; j < 8; ++j) {
        const int i = 2 * j;
        const int c1 = (i & 1) ^ p1;
        const int c2 = ((i >> 1) & 1) ^ p2;
        const int c3 = ((i >> 2) & 1) ^ p3;
        const int c4 = ((i >> 3) & 1) ^ p4;
        const int s = (c1 ? 1 : 0) ^ (c2 ? 2 : 0) ^ (c3 ? 7 : 0) ^ (c4 ? 8 : 0);
        wA[j] = -2.f * W2[lane * ST + s];
        wB[j] = -2.f * W2[(lane ^ 1) * ST + s];
    }
    v2f wA2[4], wB2[4];
    #pragma unroll
    for (int m = 0; m < 4; ++m) {
        wA2[m] = (v2f){wA[2 * m], wA[2 * m + 1]};
        wB2[m] = (v2f){wB[2 * m], wB[2 * m + 1]};
    }

    const int bp32 = ((lane ^ 32) & 63) << 2;   // ds_bpermute byte addrs
    const int bp48 = ((lane ^ 48) & 63) << 2;
    const float b20 = b2v[0];

    float V  = b1[lane] * KSCALE;               // K-scaled carry (y starts 0)
    float y0 = 0.f;

    if (lane == 0) out[b] = 0.f;                // row t=0 is zeros

    // Lane l holds x[(t0+l)*B + b]; prefetch one chunk ahead.
    float xv = x[min(lane, TM1 - 1) * BATCH + b];
    float z = fmaf(bcast(xv, 0), w1xK, V);      // z_0 (K-scaled)

    for (int t0 = 0; t0 < TM1; t0 += 64) {
        float xvn = x[min(t0 + 64 + lane, TM1 - 1) * BATCH + b];
        const int nsteps = min(64, TM1 - t0);
        float outy = 0.f;

        for (int kk = 0; kk < nsteps; ++kk) {
            // tanh in r-form: t=exp2(z); r=rcp(t+1). (h = 1-2r implicit;
            // saturation via inf/0 semantics, no clamp — R8-validated.)
            float t = __builtin_amdgcn_exp2f(z);
            float r = __builtin_amdgcn_rcpf(t + 1.f);

            // Off-chain prep for next step's z.
            const int nk = kk + 1;
            float xsrc = (nk == 64) ? xvn : xv;
            float xtn  = bcast(xsrc, nk & 63);
            float zbase = fmaf(xtn, w1xK, V);   // z' = zbase + R

            // Stage 1 (xor1, fused, packed) on r with -2-scaled weights.
            float rx = dppmov<0xB1>(r);         // quad_perm [1,0,3,2]
            v2f r2v = (v2f){r, r};
            v2f rx2 = (v2f){rx, rx};
            v2f u1p[4];
            #pragma unroll
            for (int m = 0; m < 4; ++m)
                u1p[m] = __builtin_elementwise_fma(rx2, wB2[m], r2v * wA2[m]);

            // Stage 2 (xor2 = quad_perm [2,3,0,1]).
            float u2[4];
            #pragma unroll
            for (int m = 0; m < 4; ++m)
                u2[m] = u1p[m].x + dppmov<0x4E>(u1p[m].y);

            // Stage 3 (xor7 = row_half_mirror).
            float u3a = u2[0] + dppmov<0x141>(u2[1]);
            float u3b = u2[2] + dppmov<0x141>(u2[3]);

            // Stage 4 (xor8 = row_ror:8).
            float Pb = u3a + dppmov<0x128>(u3b);

            // Cross-row combine: 3 INDEPENDENT DS ops, one latency (R6).
            int   Pi  = __builtin_bit_cast(int, Pb);
            float a16 = __builtin_bit_cast(float,
                        __builtin_amdgcn_ds_swizzle(Pi, 0x401F));       // ^16
            float a32 = __builtin_bit_cast(float,
                        __builtin_amdgcn_ds_bpermute(bp32, Pi));        // ^32
            float a48 = __builtin_bit_cast(float,
                        __builtin_amdgcn_ds_bpermute(bp48, Pi));        // ^48
            Pb = (Pb + a16) + (a32 + a48);
            // Lane holds Pb_{lane&15}; p_s = pconst_s + Pb_s.

            // y0 path: p0 = pconst0 + Pb0 (full magnitude), b20 at store.
            y0 += pconst0 + bcast(Pb, 0);
            outy = (kk == lane) ? y0 : outy;

            // R = C2 + sum_s Pb_s*w1yd[s]: 4 chains, C2 seeded; R
            // materialized at its own scale (R10's z-seeded form banned).
            float r0 = fmaf(bcast(Pb, 0), w1yd[0], C2);
            float r1 = bcast(Pb, 4)  * w1yd[4];
            float r2 = bcast(Pb, 8)  * w1yd[8];
            float r3 = bcast(Pb, 12) * w1yd[12];
            #pragma unroll
            for (int q = 1; q < 4; ++q) {
                r0 = fmaf(bcast(Pb, q),      w1yd[q],      r0);
                r1 = fmaf(bcast(Pb, 4 + q),  w1yd[4 + q],  r1);
                r2 = fmaf(bcast(Pb, 8 + q),  w1yd[8 + q],  r2);
                r3 = fmaf(bcast(Pb, 12 + q), w1yd[12 + q], r3);
            }
            float R = (r0 + r1) + (r2 + r3);

            z = zbase + R;       // critical-path tail: single add
            V = V + R;           // off-chain, feeds next step's zbase
        }

        // Store: add back n*b2[0], one IEEE div, coalesced.
        if (lane < nsteps) {
            const int n = t0 + 1 + lane;
            out[n * BATCH + b] = fmaf((float)n, b20, outy) / SRATE;
        }
        xv = xvn;
    }
}

extern "C" void kernel_launch(void* const* d_in, const int* in_sizes, int n_in,
                              void* d_out, int out_size, void* d_ws, size_t ws_size,
                              hipStream_t stream) {
    const float* x  = (const float*)d_in[0];
    const float* W1 = (const float*)d_in[1];
    const float* b1 = (const float*)d_in[2];
    const float* W2 = (const float*)d_in[3];
    const float* b2 = (const float*)d_in[4];
    float* out = (float*)d_out;

    ScaledODENetFE_kernel<<<BATCH, 64, 0, stream>>>(x, W1, b1, W2, b2, out);
}